// Round 9
// baseline (3915.561 us; speedup 1.0000x reference)
//
#include <hip/hip_runtime.h>

typedef float v2f __attribute__((ext_vector_type(2)));

#define SUB   8
#define INCH  64
#define IMH   128
#define IMW   128
#define OUTCH 128
#define OH    126
#define OW    126
#define OPLANE (OH * OW)      // 15876

#define NCH  23               // 16 owned och-pairs + 7 halo channels
#define RSW  132              // words per staged row: 128 + 4 pad (xg=31 window overrun)
#define CHW  (6 * RSW)        // 792 words per channel (6 input rows)
#define LDSW (NCH * CHW)      // 18216 words = 72864 B -> 2 blocks/CU
#define NF4  (NCH * 6 * 33)   // 4554 float4 staged

// ---- weight prep: chunk c = s*64 + p (p in [0,64)): 20 floats, 16B aligned
//      t0..8 = W[p][s][.][.],  t9..17 = W[p+64][s][.][.]
__global__ __launch_bounds__(256)
void prep_weights_kernel(const float* __restrict__ Wg, float* __restrict__ Wp) {
    int idx = blockIdx.x * 256 + threadIdx.x;
    if (idx < 512 * 18) {
        int chunk = idx / 18;
        int t     = idx - chunk * 18;
        int s = chunk >> 6;
        int p = chunk & 63;
        int o  = (t < 9) ? p : p + 64;
        int tt = (t < 9) ? t : t - 9;
        Wp[chunk * 20 + t] = Wg[(o * SUB + s) * 9 + tt];
    }
}

// Block = 16 och-pairs x 128 cols x 4 out rows. Thread (pl,xg) = 2 och x 4 rows x 4 cols.
// Wave = 2 pl x 32 xg -> LDS reads are two contiguous 512B runs (R8-proven conflict-free).
// One barrier; weights loaded per-s from L2-hot Wp (R6-proven, no big resident array).
__global__ __launch_bounds__(512, 4)
void Group_Conv_84731114815961_kernel(const float* __restrict__ X,
                                      const float* __restrict__ Wg,
                                      const float* __restrict__ Bias,
                                      const float* __restrict__ Wp,
                                      float* __restrict__ Out) {
    __shared__ float xin[LDSW];   // 72864 B

    const int g   = blockIdx.x;   // 0..3   och-pair group (p = 16g..16g+15)
    const int ty  = blockIdx.y;   // 0..31  4-row strip
    const int b   = blockIdx.z;   // 0..15
    const int y0  = ty * 4;
    const int tid = threadIdx.x;
    const int pl  = tid >> 5;     // 0..15 local och-pair
    const int xg  = tid & 31;     // 4-col group
    const int p   = g * 16 + pl;  // och pair {p, p+64}

    const float* Xb = X + (size_t)b * (INCH * IMH * IMW);

    // ---- stage 23 ch x 6 rows x 132 cols (float4, conflict-free writes) ----
    #pragma unroll
    for (int it = 0; it < 9; ++it) {
        int k = it * 512 + tid;
        if (k < NF4) {
            int ch  = k / 198;            // 198 float4 per channel
            int rem = k - ch * 198;
            int r   = rem / 33;           // 33 float4 per row (132 words)
            int col = (rem - r * 33) * 4; // 0,4,...,128
            int cg  = (g * 16 + ch) & 63;
            int sr = y0 + r; if (sr > IMH - 1) sr = IMH - 1;
            int sc = col;    if (sc > IMW - 4) sc = IMW - 4;
            const float4 v = *reinterpret_cast<const float4*>(
                Xb + (size_t)cg * (IMH * IMW) + sr * IMW + sc);
            *reinterpret_cast<float4*>(&xin[ch * CHW + r * RSW + col]) = v;
        }
    }
    __syncthreads();

    const float bz0 = Bias[p];
    const float bz1 = Bias[p + 64];

    // acc[och half][y][col pair]; bias folded into init
    v2f acc0[4][2], acc1[4][2];
    #pragma unroll
    for (int y = 0; y < 4; ++y) {
        acc0[y][0] = v2f{bz0, bz0}; acc0[y][1] = v2f{bz0, bz0};
        acc1[y][0] = v2f{bz1, bz1}; acc1[y][1] = v2f{bz1, bz1};
    }

    const bool useWp = (Wp != nullptr);

    #pragma unroll
    for (int s = 0; s < SUB; ++s) {
        float w0[9], w1[9];
        if (useWp) {
            const float4* wc = reinterpret_cast<const float4*>(Wp + ((s << 6) + p) * 20);
            const float4 f0 = wc[0], f1 = wc[1], f2 = wc[2], f3 = wc[3], f4 = wc[4];
            w0[0]=f0.x; w0[1]=f0.y; w0[2]=f0.z; w0[3]=f0.w;
            w0[4]=f1.x; w0[5]=f1.y; w0[6]=f1.z; w0[7]=f1.w; w0[8]=f2.x;
            w1[0]=f2.y; w1[1]=f2.z; w1[2]=f2.w;
            w1[3]=f3.x; w1[4]=f3.y; w1[5]=f3.z; w1[6]=f3.w; w1[7]=f4.x; w1[8]=f4.y;
        } else {
            const float* w0p = Wg + (p * SUB + s) * 9;
            const float* w1p = Wg + ((p + 64) * SUB + s) * 9;
            #pragma unroll
            for (int t = 0; t < 9; ++t) { w0[t] = w0p[t]; w1[t] = w1p[t]; }
        }

        const float* basep = &xin[(pl + s) * CHW + xg * 4];
        #pragma unroll
        for (int r = 0; r < 6; ++r) {
            const float4 a = *reinterpret_cast<const float4*>(basep + r * RSW);
            const float2 e = *reinterpret_cast<const float2*>(basep + r * RSW + 4);
            const v2f P0 = v2f{a.x, a.y};
            const v2f P1 = v2f{a.y, a.z};
            const v2f P2 = v2f{a.z, a.w};
            const v2f P3 = v2f{a.w, e.x};
            const v2f P4 = v2f{e.x, e.y};
            const v2f P[5] = {P0, P1, P2, P3, P4};
            #pragma unroll
            for (int i = 0; i < 3; ++i) {
                const int y = r - i;
                if (y >= 0 && y < 4) {
                    #pragma unroll
                    for (int j = 0; j < 3; ++j) {
                        const float s0 = w0[3 * i + j];
                        const float s1 = w1[3 * i + j];
                        const v2f w0v = v2f{s0, s0};
                        const v2f w1v = v2f{s1, s1};
                        acc0[y][0] = __builtin_elementwise_fma(P[j],     w0v, acc0[y][0]);
                        acc0[y][1] = __builtin_elementwise_fma(P[j + 2], w0v, acc0[y][1]);
                        acc1[y][0] = __builtin_elementwise_fma(P[j],     w1v, acc1[y][0]);
                        acc1[y][1] = __builtin_elementwise_fma(P[j + 2], w1v, acc1[y][1]);
                    }
                }
            }
        }
    }

    // ---- stores: per (och,row) the wave writes one contiguous 504B run ----
    const int ox = xg * 4;
    float* O0 = Out + ((size_t)(b * OUTCH + p)) * OPLANE;
    float* O1 = O0 + (size_t)64 * OPLANE;

    #pragma unroll
    for (int y = 0; y < 4; ++y) {
        const int oy = y0 + y;
        if (oy < OH) {
            float* p0 = O0 + (size_t)oy * OW + ox;
            float* p1 = O1 + (size_t)oy * OW + ox;
            if (xg < 31) {
                *reinterpret_cast<float4*>(p0) = make_float4(
                    acc0[y][0].x, acc0[y][0].y, acc0[y][1].x, acc0[y][1].y);
                *reinterpret_cast<float4*>(p1) = make_float4(
                    acc1[y][0].x, acc1[y][0].y, acc1[y][1].x, acc1[y][1].y);
            } else {  // cols 124,125 only
                *reinterpret_cast<float2*>(p0) = make_float2(acc0[y][0].x, acc0[y][0].y);
                *reinterpret_cast<float2*>(p1) = make_float2(acc1[y][0].x, acc1[y][0].y);
            }
        }
    }
}

extern "C" void kernel_launch(void* const* d_in, const int* in_sizes, int n_in,
                              void* d_out, int out_size, void* d_ws, size_t ws_size,
                              hipStream_t stream) {
    const float* X    = (const float*)d_in[0];
    const float* Wg   = (const float*)d_in[1];
    const float* Bias = (const float*)d_in[2];
    float*       Out  = (float*)d_out;

    float* Wp = nullptr;
    if (d_ws && ws_size >= 512 * 20 * sizeof(float)) {
        Wp = (float*)d_ws;
        prep_weights_kernel<<<36, 256, 0, stream>>>(Wg, Wp);
    }

    // 4 och-groups x 32 y-strips x 16 batches = 2048 blocks x 512 threads
    dim3 grid(4, 32, 16);
    Group_Conv_84731114815961_kernel<<<grid, 512, 0, stream>>>(X, Wg, Bias, Wp, Out);
}